// Round 1
// baseline (61831.494 us; speedup 1.0000x reference)
//
#include <hip/hip_runtime.h>

typedef _Float16 f16x8 __attribute__((ext_vector_type(8)));
typedef float f32x4 __attribute__((ext_vector_type(4)));

#define DEVI __device__ __forceinline__

// ---- geometry ----
#define KS 27                 // K steps of 32 (850 padded to 864)
#define JT 54                 // 16-wide j tiles per half (864/16)
#define HP 864
#define N2P 1728
#define SLOT 55296            // 64*864 fp16 elements per time slot
#define PACKE 1492992ull      // 108*27*512 elements per packed matrix

// ---- ws offsets (bytes), all 256-aligned; total ~132.6 MB ----
#define OFF_WPACK 0ull
#define OFF_EMBP  59719680ull
#define OFF_X1    76999680ull
#define OFF_OUT1  84741120ull
#define OFF_OUT2  92593152ull
#define OFF_E     100445184ull
#define OFF_ST    131410944ull
#define OFF_STATS 132406272ull
#define OFF_BAR   132585472ull

DEVI float sigf(float x) { return 1.f / (1.f + __expf(-x)); }
DEVI float actf(float x, int act) {
  if (act == 0) { float e = __expf(2.f * x); return 1.f - 2.f / (e + 1.f); } // tanh
  if (act == 1) return fmaxf(x, 0.f);                                        // relu
  if (act == 2) return sigf(x);                                              // sigmoid
  return x;                                                                  // identity
}

// ---------------- prep kernels ----------------

// Pack 20 weight matrices (per layer: W0x, W0h, Ws[0..7]) into MFMA-B fragment order.
// dst element layout: [mi][nt][ks][lane][j8]; value = W[k][origcol] (0 in pads).
__global__ void __launch_bounds__(256) k_pack_w(const float* __restrict__ W0a, const float* __restrict__ Wsa,
                                                const float* __restrict__ W0b, const float* __restrict__ Wsb,
                                                _Float16* __restrict__ dst) {
  int idx = blockIdx.x * 256 + threadIdx.x;      // exactly 20*108*27*64 = 3,732,480
  int lane = idx & 63;
  int t1 = idx >> 6;
  int ks = t1 % 27;
  int t2 = t1 / 27;
  int nt = t2 % 108;
  int mi = t2 / 108;
  int layer = mi / 10, which = mi % 10;
  const float* src;
  if (which == 0)      src = layer ? W0b : W0a;                       // W0x = W0 rows 0..849
  else if (which == 1) src = (layer ? W0b : W0a) + 850 * 1700;        // W0h = W0 rows 850..1699
  else                 src = (layer ? Wsb : Wsa) + (size_t)(which - 2) * 850 * 1700;
  int np = nt * 16 + (lane & 15);
  int oc;                                        // original output column, -1 => pad
  if (np < 850) oc = np;
  else if (np < 864) oc = -1;
  else if (np < 1714) oc = np - 14;              // h half: orig col 850 + (np-864)
  else oc = -1;
  int k0 = ks * 32 + (lane >> 4) * 8;
  f16x8 v;
#pragma unroll
  for (int j = 0; j < 8; ++j) {
    int k = k0 + j;
    float f = (oc >= 0 && k < 850) ? src[(size_t)k * 1700 + oc] : 0.f;
    v[j] = (_Float16)f;
  }
  *(f16x8*)(dst + (size_t)mi * PACKE + ((size_t)(nt * 27 + ks) * 64 + lane) * 8) = v;
}

// Pack emb_w^T (K=850->864, N=10000) into B-fragment order for the decoder.
__global__ void __launch_bounds__(256) k_pack_emb(const float* __restrict__ emb, _Float16* __restrict__ dst) {
  int idx = blockIdx.x * 256 + threadIdx.x;
  if (idx >= 625 * 27 * 64) return;
  int lane = idx & 63;
  int t1 = idx >> 6;
  int ks = t1 % 27;
  int nt = t1 / 27;
  int v0 = nt * 16 + (lane & 15);
  int k0 = ks * 32 + (lane >> 4) * 8;
  f16x8 w;
#pragma unroll
  for (int j = 0; j < 8; ++j) {
    int k = k0 + j;
    w[j] = (_Float16)((k < 850) ? emb[(size_t)v0 * 850 + k] : 0.f);
  }
  *(f16x8*)(dst + ((size_t)(nt * 27 + ks) * 64 + lane) * 8) = w;
}

// Embedding lookup -> X1 fp16 [4480][864] (zero pads).
__global__ void __launch_bounds__(256) k_embed(const int* __restrict__ tok, const float* __restrict__ emb,
                                               _Float16* __restrict__ X) {
  int idx = blockIdx.x * 256 + threadIdx.x;      // exactly 4480*108
  if (idx >= 4480 * 108) return;
  int k8 = idx % 108, r = idx / 108;
  int t = tok[r];
  f16x8 v;
#pragma unroll
  for (int j = 0; j < 8; ++j) {
    int k = k8 * 8 + j;
    v[j] = (_Float16)((k < 850) ? emb[(size_t)t * 850 + k] : 0.f);
  }
  *(f16x8*)(X + (size_t)r * HP + k8 * 8) = v;
}

// h0 -> out1 slot0 (fp16, zero pads); zero the two barrier blocks.
__global__ void __launch_bounds__(256) k_init(const float* __restrict__ h0, _Float16* __restrict__ out1,
                                              unsigned* __restrict__ bar) {
  int idx = blockIdx.x * 256 + threadIdx.x;
  if (idx < 64 * 108) {
    int k8 = idx % 108, b = idx / 108;
    f16x8 v;
#pragma unroll
    for (int j = 0; j < 8; ++j) {
      int k = k8 * 8 + j;
      v[j] = (_Float16)((k < 850) ? h0[(size_t)b * 850 + k] : 0.f);
    }
    *(f16x8*)(out1 + (size_t)b * HP + k8 * 8) = v;
  } else if (idx < 64 * 108 + 64) {
    bar[idx - 64 * 108] = 0u;
  }
}

// out2 slot0 = out1 slot70
__global__ void __launch_bounds__(256) k_copy(const _Float16* __restrict__ s, _Float16* __restrict__ d) {
  int idx = blockIdx.x * 256 + threadIdx.x;      // exactly 13824
  ((f16x8*)d)[idx] = ((const f16x8*)(s + (size_t)70 * SLOT))[idx];
}

// E = X @ W0x_pack  (M=4480, N=1728 as c/h tile pairs), f32 out.
__global__ void __launch_bounds__(256) k_gemmE(const _Float16* __restrict__ X, const _Float16* __restrict__ Wx,
                                               float* __restrict__ E) {
  int lane = threadIdx.x & 63;
  int wid = blockIdx.x * 4 + (threadIdx.x >> 6);
  int nw = gridDim.x * 4;
  int col = lane & 15, rg = lane >> 4;
  for (int tt = wid; tt < 280 * 54; tt += nw) {
    int m = tt / 54, j = tt % 54;
    f32x4 ac = {0.f, 0.f, 0.f, 0.f}, ah = {0.f, 0.f, 0.f, 0.f};
    const _Float16* ap = X + (size_t)(m * 16 + col) * HP + rg * 8;
    const _Float16* bc = Wx + ((size_t)(j * 27) * 64 + lane) * 8;
    const _Float16* bh = Wx + ((size_t)((j + 54) * 27) * 64 + lane) * 8;
    for (int ks = 0; ks < KS; ++ks) {
      f16x8 a = *(const f16x8*)(ap + ks * 32);
      f16x8 wc = *(const f16x8*)(bc + (size_t)ks * 512);
      f16x8 wh = *(const f16x8*)(bh + (size_t)ks * 512);
      ac = __builtin_amdgcn_mfma_f32_16x16x32_f16(a, wc, ac, 0, 0, 0);
      ah = __builtin_amdgcn_mfma_f32_16x16x32_f16(a, wh, ah, 0, 0, 0);
    }
#pragma unroll
    for (int r = 0; r < 4; ++r) {
      int row = m * 16 + rg * 4 + r;
      E[(size_t)row * N2P + j * 16 + col] = ac[r];
      E[(size_t)row * N2P + 864 + j * 16 + col] = ah[r];
    }
  }
}

// ---------------- recurrence ----------------

// device-scope sense-reversal barrier across 256 workgroups
DEVI void gbar(unsigned* bar, unsigned target) {
  __syncthreads();
  if (threadIdx.x == 0) {
    __threadfence();  // agent release: L2 writeback so other XCDs see our stores
    unsigned my = __hip_atomic_fetch_add(bar + 0, 1u, __ATOMIC_ACQ_REL, __HIP_MEMORY_SCOPE_AGENT);
    if (my == 255u) {
      __hip_atomic_store(bar + 0, 0u, __ATOMIC_RELAXED, __HIP_MEMORY_SCOPE_AGENT);
      __hip_atomic_store(bar + 1, target, __ATOMIC_RELEASE, __HIP_MEMORY_SCOPE_AGENT);
    } else {
      while (__hip_atomic_load(bar + 1, __ATOMIC_ACQUIRE, __HIP_MEMORY_SCOPE_AGENT) != target)
        __builtin_amdgcn_s_sleep(2);
    }
  }
  __syncthreads();
}

template <int NM>
DEVI void mmN(const _Float16* __restrict__ A, const _Float16* const* W, int m, int j, int lane,
              f32x4* cc, f32x4* ch) {
  const _Float16* ap = A + (size_t)(m * 16 + (lane & 15)) * HP + (lane >> 4) * 8;
  const size_t oc = (size_t)(j * 27) * 512 + (size_t)lane * 8;
  const size_t oh = (size_t)((j + 54) * 27) * 512 + (size_t)lane * 8;
  for (int ks = 0; ks < KS; ++ks) {
    f16x8 a = *(const f16x8*)(ap + ks * 32);
#pragma unroll
    for (int q = 0; q < NM; ++q) {
      f16x8 wc = *(const f16x8*)(W[q] + oc + (size_t)ks * 512);
      f16x8 wh = *(const f16x8*)(W[q] + oh + (size_t)ks * 512);
      cc[q] = __builtin_amdgcn_mfma_f32_16x16x32_f16(a, wc, cc[q], 0, 0, 0);
      ch[q] = __builtin_amdgcn_mfma_f32_16x16x32_f16(a, wh, ch[q], 0, 0, 0);
    }
  }
}

DEVI void gate_store(const _Float16* __restrict__ sp, _Float16* __restrict__ dst,
                     int m, int j, int lane, const f32x4& c, const f32x4& h, int act) {
  int col = lane & 15, rg = lane >> 4;
  int jc = j * 16 + col;
#pragma unroll
  for (int r = 0; r < 4; ++r) {
    int row = m * 16 + rg * 4 + r;
    float spv = (jc < 850) ? (float)sp[(size_t)row * HP + jc] : 0.f;
    float g = sigf(c[r]);
    float a = actf(h[r], act);
    float sv = spv + g * (a - spv);
    dst[(size_t)row * HP + jc] = (jc < 850) ? (_Float16)sv : (_Float16)0.f;
  }
}

// One RNN layer: 70 cells, 5 barrier-separated levels each. Grid MUST be 256x256 (cooperative).
__global__ void __launch_bounds__(256) k_layer(const _Float16* __restrict__ Wp, const float* __restrict__ E,
                                               _Float16* __restrict__ outb, _Float16* __restrict__ st,
                                               unsigned* __restrict__ bar) {
  const int lane = threadIdx.x & 63;
  const int wid = blockIdx.x * 4 + (threadIdx.x >> 6);
  const int col = lane & 15, rg = lane >> 4;
  unsigned ep = 0;
  const _Float16* W0h = Wp + PACKE;
  const _Float16* Wn0 = Wp + 2 * PACKE;
  const _Float16* Wn1 = Wp + 3 * PACKE;
  const _Float16* Wn2 = Wp + 4 * PACKE;
  const _Float16* Wn3 = Wp + 5 * PACKE;
  const _Float16* Wn4 = Wp + 6 * PACKE;
  const _Float16* Wn5 = Wp + 7 * PACKE;
  const _Float16* Wn6 = Wp + 8 * PACKE;
  const _Float16* Wn7 = Wp + 9 * PACKE;
  _Float16* S0 = st;
  _Float16* S1 = st + 1 * SLOT;
  _Float16* S2 = st + 2 * SLOT;
  _Float16* S3 = st + 3 * SLOT;
  _Float16* S4 = st + 4 * SLOT;
  _Float16* S5 = st + 5 * SLOT;
  _Float16* S7 = st + 7 * SLOT;

  for (int t = 0; t < 70; ++t) {
    const _Float16* hp = outb + (size_t)t * SLOT;
    // L0: z0 = E[t] + h@W0h ; s0 = h + sig(c)*(tanh(h)-h)
    for (int tt = wid; tt < 216; tt += 1024) {
      int m = tt / 54, j = tt % 54;
      f32x4 ac, ah;
#pragma unroll
      for (int r = 0; r < 4; ++r) {
        size_t row = (size_t)(t * 64 + m * 16 + rg * 4 + r) * N2P;
        ac[r] = E[row + j * 16 + col];
        ah[r] = E[row + 864 + j * 16 + col];
      }
      const _Float16* Wl[1] = {W0h};
      mmN<1>(hp, Wl, m, j, lane, &ac, &ah);
      gate_store(hp, S0, m, j, lane, ac, ah, 0);
    }
    gbar(bar, ++ep);
    // L1: s1 = gate(s0; Ws0, sigmoid)
    for (int tt = wid; tt < 216; tt += 1024) {
      int m = tt / 54, j = tt % 54;
      f32x4 ac = {0.f, 0.f, 0.f, 0.f}, ah = {0.f, 0.f, 0.f, 0.f};
      const _Float16* Wl[1] = {Wn0};
      mmN<1>(S0, Wl, m, j, lane, &ac, &ah);
      gate_store(S0, S1, m, j, lane, ac, ah, 2);
    }
    gbar(bar, ++ep);
    // L2: s2,s3 (relu), s4 (identity) all from s1
    for (int tt = wid; tt < 216; tt += 1024) {
      int m = tt / 54, j = tt % 54;
      f32x4 cc[3] = {{0.f,0.f,0.f,0.f},{0.f,0.f,0.f,0.f},{0.f,0.f,0.f,0.f}};
      f32x4 hh[3] = {{0.f,0.f,0.f,0.f},{0.f,0.f,0.f,0.f},{0.f,0.f,0.f,0.f}};
      const _Float16* Wl[3] = {Wn1, Wn2, Wn3};
      mmN<3>(S1, Wl, m, j, lane, cc, hh);
      gate_store(S1, S2, m, j, lane, cc[0], hh[0], 1);
      gate_store(S1, S3, m, j, lane, cc[1], hh[1], 1);
      gate_store(S1, S4, m, j, lane, cc[2], hh[2], 3);
    }
    gbar(bar, ++ep);
    // L3: s5 = tanh-gate(s2; Ws4), s7 = tanh-gate(s3; Ws6)
    for (int tt = wid; tt < 432; tt += 1024) {
      int sub = tt / 216, q = tt % 216;
      int m = q / 54, j = q % 54;
      f32x4 ac = {0.f, 0.f, 0.f, 0.f}, ah = {0.f, 0.f, 0.f, 0.f};
      const _Float16* A = sub ? S3 : S2;
      const _Float16* Wl[1] = {sub ? Wn6 : Wn4};
      mmN<1>(A, Wl, m, j, lane, &ac, &ah);
      gate_store(A, sub ? S7 : S5, m, j, lane, ac, ah, 0);
    }
    gbar(bar, ++ep);
    // L4: s6 (sigmoid), s8 (relu) from s5; h_new = mean(s1..s8) -> out slot t+1
    for (int tt = wid; tt < 216; tt += 1024) {
      int m = tt / 54, j = tt % 54;
      f32x4 cc[2] = {{0.f,0.f,0.f,0.f},{0.f,0.f,0.f,0.f}};
      f32x4 hh[2] = {{0.f,0.f,0.f,0.f},{0.f,0.f,0.f,0.f}};
      const _Float16* Wl[2] = {Wn5, Wn7};
      mmN<2>(S5, Wl, m, j, lane, cc, hh);
      _Float16* outn = outb + (size_t)(t + 1) * SLOT;
      int jc = j * 16 + col;
#pragma unroll
      for (int r = 0; r < 4; ++r) {
        size_t row = (size_t)(m * 16 + rg * 4 + r) * HP;
        float s5v = (jc < 850) ? (float)S5[row + jc] : 0.f;
        float s6 = s5v + sigf(cc[0][r]) * (sigf(hh[0][r]) - s5v);
        float s8 = s5v + sigf(cc[1][r]) * (fmaxf(hh[1][r], 0.f) - s5v);
        float acc = s5v + s6 + s8;
        if (jc < 850) {
          acc += (float)S1[row + jc] + (float)S2[row + jc] + (float)S3[row + jc] +
                 (float)S4[row + jc] + (float)S7[row + jc];
        }
        outn[row + jc] = (jc < 850) ? (_Float16)(acc * 0.125f) : (_Float16)0.f;
      }
    }
    gbar(bar, ++ep);
  }
}

// ---------------- decoder ----------------

// pass1: per-row online max / sum-exp over 5 v-chunks (2000 cols each)
__global__ void __launch_bounds__(256) k_dec1(const _Float16* __restrict__ A, const _Float16* __restrict__ EP,
                                              const float* __restrict__ bias, float* __restrict__ stats) {
  int lane = threadIdx.x & 63;
  int wid = blockIdx.x * 4 + (threadIdx.x >> 6);
  int nw = gridDim.x * 4;
  int col = lane & 15, rg = lane >> 4;
  for (int tt = wid; tt < 280 * 5; tt += nw) {
    int mt = tt / 5, ch = tt % 5;
    float mx[4] = {-1e30f, -1e30f, -1e30f, -1e30f}, sm[4] = {0.f, 0.f, 0.f, 0.f};
    const _Float16* ap = A + (size_t)(mt * 16 + col) * HP + rg * 8;
    for (int vt = ch * 125; vt < ch * 125 + 125; ++vt) {
      f32x4 acc = {0.f, 0.f, 0.f, 0.f};
      const _Float16* bp = EP + ((size_t)(vt * 27) * 64 + lane) * 8;
      for (int ks = 0; ks < KS; ++ks) {
        f16x8 a = *(const f16x8*)(ap + ks * 32);
        f16x8 b = *(const f16x8*)(bp + (size_t)ks * 512);
        acc = __builtin_amdgcn_mfma_f32_16x16x32_f16(a, b, acc, 0, 0, 0);
      }
      float bv = bias[vt * 16 + col];
#pragma unroll
      for (int r = 0; r < 4; ++r) {
        float l = acc[r] + bv;
        float mn = fmaxf(mx[r], l);
        sm[r] = sm[r] * __expf(mx[r] - mn) + __expf(l - mn);
        mx[r] = mn;
      }
    }
#pragma unroll
    for (int d = 1; d < 16; d <<= 1) {
#pragma unroll
      for (int r = 0; r < 4; ++r) {
        float mo = __shfl_xor(mx[r], d, 64);
        float so = __shfl_xor(sm[r], d, 64);
        float mn = fmaxf(mx[r], mo);
        sm[r] = sm[r] * __expf(mx[r] - mn) + so * __expf(mo - mn);
        mx[r] = mn;
      }
    }
    if (col == 0) {
#pragma unroll
      for (int r = 0; r < 4; ++r) {
        size_t row = (size_t)(mt * 16 + rg * 4 + r);
        stats[(row * 5 + ch) * 2 + 0] = mx[r];
        stats[(row * 5 + ch) * 2 + 1] = sm[r];
      }
    }
  }
}

// pass2: recompute logits, write log_softmax (f32)
__global__ void __launch_bounds__(256) k_dec2(const _Float16* __restrict__ A, const _Float16* __restrict__ EP,
                                              const float* __restrict__ bias, const float* __restrict__ stats,
                                              float* __restrict__ out) {
  int lane = threadIdx.x & 63;
  int wid = blockIdx.x * 4 + (threadIdx.x >> 6);
  int nw = gridDim.x * 4;
  int col = lane & 15, rg = lane >> 4;
  for (int tt = wid; tt < 280 * 5; tt += nw) {
    int mt = tt / 5, ch = tt % 5;
    float LSE[4];
#pragma unroll
    for (int r = 0; r < 4; ++r) {
      size_t row = (size_t)(mt * 16 + rg * 4 + r);
      float m = -1e30f, s = 0.f;
      for (int c5 = 0; c5 < 5; ++c5) {
        float mm = stats[(row * 5 + c5) * 2 + 0];
        float ss = stats[(row * 5 + c5) * 2 + 1];
        float mn = fmaxf(m, mm);
        s = s * __expf(m - mn) + ss * __expf(mm - mn);
        m = mn;
      }
      LSE[r] = m + __logf(s);
    }
    const _Float16* ap = A + (size_t)(mt * 16 + col) * HP + rg * 8;
    for (int vt = ch * 125; vt < ch * 125 + 125; ++vt) {
      f32x4 acc = {0.f, 0.f, 0.f, 0.f};
      const _Float16* bp = EP + ((size_t)(vt * 27) * 64 + lane) * 8;
      for (int ks = 0; ks < KS; ++ks) {
        f16x8 a = *(const f16x8*)(ap + ks * 32);
        f16x8 b = *(const f16x8*)(bp + (size_t)ks * 512);
        acc = __builtin_amdgcn_mfma_f32_16x16x32_f16(a, b, acc, 0, 0, 0);
      }
      float bv = bias[vt * 16 + col];
#pragma unroll
      for (int r = 0; r < 4; ++r) {
        size_t row = (size_t)(mt * 16 + rg * 4 + r);
        out[row * 10000 + vt * 16 + col] = acc[r] + bv - LSE[r];
      }
    }
  }
}

// ---------------- launch ----------------

extern "C" void kernel_launch(void* const* d_in, const int* in_sizes, int n_in,
                              void* d_out, int out_size, void* d_ws, size_t ws_size,
                              hipStream_t stream) {
  const int* tokens = (const int*)d_in[0];
  const float* h0 = (const float*)d_in[1];
  const float* emb = (const float*)d_in[2];
  const float* decb = (const float*)d_in[3];
  const float* W0_1 = (const float*)d_in[4];
  const float* Ws_1 = (const float*)d_in[5];
  const float* W0_2 = (const float*)d_in[6];
  const float* Ws_2 = (const float*)d_in[7];
  float* out = (float*)d_out;
  char* ws = (char*)d_ws;

  _Float16* wpack = (_Float16*)(ws + OFF_WPACK);
  _Float16* embp = (_Float16*)(ws + OFF_EMBP);
  _Float16* x1 = (_Float16*)(ws + OFF_X1);
  _Float16* out1 = (_Float16*)(ws + OFF_OUT1);
  _Float16* out2 = (_Float16*)(ws + OFF_OUT2);
  float* E = (float*)(ws + OFF_E);
  _Float16* st = (_Float16*)(ws + OFF_ST);
  float* stats = (float*)(ws + OFF_STATS);
  unsigned* bar = (unsigned*)(ws + OFF_BAR);

  k_pack_w<<<14580, 256, 0, stream>>>(W0_1, Ws_1, W0_2, Ws_2, wpack);
  k_pack_emb<<<4220, 256, 0, stream>>>(emb, embp);
  k_embed<<<1890, 256, 0, stream>>>(tokens, emb, x1);
  k_init<<<28, 256, 0, stream>>>(h0, out1, bar);
  k_gemmE<<<1024, 256, 0, stream>>>(x1, wpack, E);  // E1 = emb @ W0x_1

  {
    const _Float16* Wp = wpack;
    const float* Ec = E;
    _Float16* ob = out1;
    _Float16* stp = st;
    unsigned* b0 = bar;
    void* args[] = {&Wp, &Ec, &ob, &stp, &b0};
    hipLaunchCooperativeKernel(reinterpret_cast<void*>(k_layer), dim3(256), dim3(256), args, 0, stream);
  }

  k_copy<<<54, 256, 0, stream>>>(out1, out2);
  k_gemmE<<<1024, 256, 0, stream>>>(out1 + (size_t)SLOT, wpack + 10 * PACKE, E);  // E2 = out1 @ W0x_2

  {
    const _Float16* Wp = wpack + 10 * PACKE;
    const float* Ec = E;
    _Float16* ob = out2;
    _Float16* stp = st;
    unsigned* b1 = bar + 32;
    void* args[] = {&Wp, &Ec, &ob, &stp, &b1};
    hipLaunchCooperativeKernel(reinterpret_cast<void*>(k_layer), dim3(256), dim3(256), args, 0, stream);
  }

  k_dec1<<<512, 256, 0, stream>>>(out2 + (size_t)SLOT, embp, decb, stats);
  k_dec2<<<512, 256, 0, stream>>>(out2 + (size_t)SLOT, embp, decb, stats, out);
}